// Round 6
// baseline (12088.061 us; speedup 1.0000x reference)
//
#include <hip/hip_runtime.h>

#define D 512
#define TW 16

__device__ __forceinline__ float waveSum(float v) {
#pragma unroll
    for (int m = 32; m > 0; m >>= 1) v += __shfl_xor(v, m, 64);
    return v;
}
__device__ __forceinline__ float waveMin(float v) {
#pragma unroll
    for (int m = 32; m > 0; m >>= 1) v = fminf(v, __shfl_xor(v, m, 64));
    return v;
}
__device__ __forceinline__ float waveMax(float v) {
#pragma unroll
    for (int m = 32; m > 0; m >>= 1) v = fmaxf(v, __shfl_xor(v, m, 64));
    return v;
}

// ---------------- Kernel 0: xT[d][n] = x[n][d]. grid (32, 8), 256 thr ----------
__global__ __launch_bounds__(256) void xpose_kernel(const float* __restrict__ x,
                                                    float* __restrict__ xT) {
    __shared__ float t[64][65];
    const int bx = blockIdx.x * 64;  // n block
    const int by = blockIdx.y * 64;  // d block
    const int tid = threadIdx.x;
    const int lx = tid & 63, lq = tid >> 6;
#pragma unroll
    for (int r = 0; r < 64; r += 4)
        t[r + lq][lx] = x[(size_t)(bx + r + lq) * D + by + lx];
    __syncthreads();
#pragma unroll
    for (int r = 0; r < 64; r += 4)
        xT[(size_t)(by + r + lq) * 2048 + bx + lx] = t[lx][r + lq];
}

// ---------------- Kernel 1: m = A^T A (per s). grid (64 tiles, 64 s), 256 thr ----
__global__ __launch_bounds__(256) void syrk_kernel(const float* __restrict__ sp,
                                                   float* __restrict__ M) {
    const int s = blockIdx.y;
    const int I = blockIdx.x >> 3, J = blockIdx.x & 7;
    const int tx = threadIdx.x & 15, ty = threadIdx.x >> 4;
    const float* __restrict__ A = sp + (size_t)s * D * D;
    __shared__ __align__(16) float As[64 * 68];
    __shared__ __align__(16) float Bs[64 * 68];
    float acc[4][4];
#pragma unroll
    for (int r = 0; r < 4; r++)
#pragma unroll
        for (int q = 0; q < 4; q++) acc[r][q] = 0.f;

    for (int k0 = 0; k0 < D; k0 += 64) {
        for (int e = threadIdx.x; e < 4096; e += 256) {
            const int col = e & 63, kr = e >> 6;
            As[kr * 68 + col] = A[(size_t)(k0 + kr) * D + I * 64 + col];
            Bs[kr * 68 + col] = A[(size_t)(k0 + kr) * D + J * 64 + col];
        }
        __syncthreads();
#pragma unroll 4
        for (int k = 0; k < 64; k++) {
            const float4 a = *(const float4*)&As[k * 68 + 4 * ty];
            const float4 b = *(const float4*)&Bs[k * 68 + 4 * tx];
            const float av[4] = {a.x, a.y, a.z, a.w};
            const float bv[4] = {b.x, b.y, b.z, b.w};
#pragma unroll
            for (int r = 0; r < 4; r++)
#pragma unroll
                for (int q = 0; q < 4; q++) acc[r][q] += av[r] * bv[q];
        }
        __syncthreads();
    }
#pragma unroll
    for (int r = 0; r < 4; r++) {
        float4 v4;
        v4.x = acc[r][0]; v4.y = acc[r][1]; v4.z = acc[r][2]; v4.w = acc[r][3];
        const size_t off = (size_t)s * D * D + (size_t)(I * 64 + 4 * ty + r) * D + J * 64 + 4 * tx;
        *(float4*)(M + off) = v4;
    }
}

// ---------------- Kernel 2a: LATRD panel v3 (symmetric tiled symv) --------------
// 64 WGs x 1024 thr. symv reads only lower-triangle 64x64 tiles; off-diag tiles
// used twice (direct + transpose pass). Accumulation into pf via LDS atomics.
__global__ __launch_bounds__(1024) void latrd_panel(float* __restrict__ T,
                                                    float* __restrict__ Vt,
                                                    float* __restrict__ Wt,
                                                    float* __restrict__ dvec,
                                                    float* __restrict__ evec,
                                                    int ps, int jmax) {
    const int s = blockIdx.x;
    float* __restrict__ Ts = T + (size_t)s * D * D;
    float* __restrict__ Vg = Vt + (size_t)s * 32 * D;
    float* __restrict__ Wg = Wt + (size_t)s * 32 * D;
    const int tid = threadIdx.x, lane = tid & 63, wid = tid >> 6;
    const int l4 = lane & 15, quad = lane >> 4;
    extern __shared__ float sm[];
    float* __restrict__ Vs = sm;              // 512*33
    float* __restrict__ Ws = sm + 16896;      // 512*33
    float* __restrict__ vb = sm + 33792;      // 512
    float* __restrict__ pf = sm + 34304;      // 512
    float* __restrict__ c1 = sm + 34816;      // 32
    float* __restrict__ c2 = sm + 34848;      // 32
    float* __restrict__ red = sm + 34880;     // 16
    float* __restrict__ sca = sm + 34896;     // 4

    for (int i = tid; i < 34304; i += 1024) sm[i] = 0.f;  // Vs, Ws, vb
    __syncthreads();

    float rk = (tid < D) ? Ts[(size_t)ps * D + tid] : 0.f;

    for (int j = 0; j < jmax; j++) {
        const int k = ps + j, sup = k + 1;
        // ---- S1: corrected pivot row -> vb, pf zero, xn2 partials ----
        float val = 0.f;
        if (tid < D) pf[tid] = 0.f;
        if (tid < D && tid > k) {
            float corr = 0.f;
#pragma unroll 4
            for (int t = 0; t < j; t++)
                corr += Vs[tid * 33 + t] * Ws[k * 33 + t]
                      + Ws[tid * 33 + t] * Vs[k * 33 + t];
            val = rk - corr;
            vb[tid] = val;
            if (tid == sup) sca[3] = val;  // a0
        } else if (tid == k) {
            float dc = 0.f;
            for (int t = 0; t < j; t++) dc += Vs[k * 33 + t] * Ws[k * 33 + t];
            dvec[s * D + k] = rk - 2.f * dc;
            vb[k] = 0.f;
        }
        float xp = (tid < D && tid > sup) ? val * val : 0.f;
        xp = waveSum(xp);
        if (lane == 0) red[wid] = xp;
        __syncthreads();                                   // B1

        // ---- S2: all threads: xn2, beta, v0; 32-groups: c1/c2 ----
        float xn2 = 0.f;
#pragma unroll
        for (int q = 0; q < TW; q++) xn2 += red[q];
        const float a0 = sca[3];
        const int skip = (xn2 <= 0.f);
        float beta = 0.f, v0 = 0.f, alpha = a0;
        if (!skip) {
            const float an = sqrtf(a0 * a0 + xn2);
            alpha = (a0 >= 0.f) ? -an : an;
            v0 = a0 - alpha;
            beta = 2.f / (v0 * v0 + xn2);
        }
        if (tid == sup) {
            evec[s * D + k] = skip ? a0 : alpha;
            if (!skip) vb[sup] = v0;
        }
        if (!skip) {
            const int t = tid >> 5, r = tid & 31;
            float a1 = 0.f, a2 = 0.f;
            for (int i = sup + 1 + r; i < D; i += 32) {
                const float v = vb[i];
                a1 += Ws[i * 33 + t] * v;
                a2 += Vs[i * 33 + t] * v;
            }
#pragma unroll
            for (int m = 16; m > 0; m >>= 1) {
                a1 += __shfl_xor(a1, m, 64);
                a2 += __shfl_xor(a2, m, 64);
            }
            if (r == 0) {
                c1[t] = a1 + Ws[sup * 33 + t] * v0;
                c2[t] = a2 + Vs[sup * 33 + t] * v0;
            }
        }
        __syncthreads();                                   // B2
        if (skip) {
            if (tid < D && tid >= sup) { Vg[j * D + tid] = 0.f; Wg[j * D + tid] = 0.f; }
            if (tid < D && k + 1 < D) rk = Ts[(size_t)(k + 1) * D + tid];
            __syncthreads();
            continue;
        }

        // ---- S3: symmetric tiled symv -> pf (raw A*v, lower tiles only) ----
        {
            const int b0 = sup >> 6, tb = 8 - b0, ntile = tb * (tb + 1) / 2;
            for (int tt = wid; tt < ntile; tt += TW) {
                int ri = 0, acc0 = 0;
                while (acc0 + ri + 1 <= tt) { acc0 += ri + 1; ri++; }
                const int cj = tt - acc0;
                const int gi0 = (b0 + ri) << 6, gj0 = (b0 + cj) << 6;
                // pass A: p[gi0+rr] += tile_row . vb[gj0..]
                for (int rr = quad; rr < 64; rr += 4) {
                    const float4 a = *(const float4*)&Ts[(size_t)(gi0 + rr) * D + gj0 + 4 * l4];
                    const float4 b = *(const float4*)&vb[gj0 + 4 * l4];
                    float sum = a.x * b.x + a.y * b.y + a.z * b.z + a.w * b.w;
                    sum += __shfl_xor(sum, 1, 64);
                    sum += __shfl_xor(sum, 2, 64);
                    sum += __shfl_xor(sum, 4, 64);
                    sum += __shfl_xor(sum, 8, 64);
                    if (l4 == 0) atomicAdd(&pf[gi0 + rr], sum);
                }
                if (ri != cj) {
                    // pass B: p[gj0+lane] += sum_rr tile[rr][lane]*vb[gi0+rr]
                    const float* __restrict__ base = Ts + (size_t)gi0 * D + gj0 + lane;
                    float y0 = 0.f, y1 = 0.f, y2 = 0.f, y3 = 0.f;
#pragma unroll 4
                    for (int rr = 0; rr < 64; rr += 4) {
                        y0 += base[(size_t)(rr    ) * D] * vb[gi0 + rr];
                        y1 += base[(size_t)(rr + 1) * D] * vb[gi0 + rr + 1];
                        y2 += base[(size_t)(rr + 2) * D] * vb[gi0 + rr + 2];
                        y3 += base[(size_t)(rr + 3) * D] * vb[gi0 + rr + 3];
                    }
                    atomicAdd(&pf[gj0 + lane], (y0 + y1) + (y2 + y3));
                }
            }
        }
        __syncthreads();                                   // B3

        // ---- S4: per-row V/W correction, scale by beta, pv partials ----
        float pvp = 0.f;
        if (tid < D && tid >= sup) {
            float corr = 0.f;
#pragma unroll 8
            for (int t = 0; t < 32; t++)
                corr += Vs[tid * 33 + t] * c1[t] + Ws[tid * 33 + t] * c2[t];
            const float p = beta * (pf[tid] - corr);
            pf[tid] = p;
            pvp = p * vb[tid];
        }
        pvp = waveSum(pvp);
        if (lane == 0) red[wid] = pvp;
        __syncthreads();                                   // B4

        // ---- S5: w = p - c*v; store V/W; prefetch next pivot row ----
        float pv = 0.f;
#pragma unroll
        for (int q = 0; q < TW; q++) pv += red[q];
        const float cc = 0.5f * beta * pv;
        if (tid < D) {
            if (tid >= sup) {
                const float v = vb[tid];
                const float w = pf[tid] - cc * v;
                Vs[tid * 33 + j] = v;
                Ws[tid * 33 + j] = w;
                Vg[j * D + tid] = v;
                Wg[j * D + tid] = w;
            }
            if (k + 1 < D) rk = Ts[(size_t)(k + 1) * D + tid];
        }
        __syncthreads();                                   // B5
    }
    if (ps + jmax == D - 2 && tid == 0) {
        const int k1 = D - 2, k2 = D - 1;
        float dc = 0.f, ec = 0.f, dc2 = 0.f;
        for (int t = 0; t < jmax; t++) {
            dc  += Vs[k1 * 33 + t] * Ws[k1 * 33 + t];
            ec  += Vs[k1 * 33 + t] * Ws[k2 * 33 + t]
                 + Ws[k1 * 33 + t] * Vs[k2 * 33 + t];
            dc2 += Vs[k2 * 33 + t] * Ws[k2 * 33 + t];
        }
        dvec[s * D + k1] = Ts[(size_t)k1 * D + k1] - 2.f * dc;
        evec[s * D + k1] = Ts[(size_t)k1 * D + k2] - ec;
        dvec[s * D + k2] = Ts[(size_t)k2 * D + k2] - 2.f * dc2;
        evec[s * D + k2] = 0.f;
    }
}

// ---------------- Kernel 2b: rank-64 symmetric update A -= V W^T + W V^T --------
__global__ __launch_bounds__(256) void latrd_update(float* __restrict__ T,
                                                    const float* __restrict__ Vt,
                                                    const float* __restrict__ Wt,
                                                    int r0) {
    const int s = blockIdx.z;
    const int i0 = r0 + 64 * blockIdx.y;
    const int j0 = r0 + 64 * blockIdx.x;
    float* __restrict__ Ts = T + (size_t)s * D * D;
    const float* __restrict__ Vg = Vt + (size_t)s * 32 * D;
    const float* __restrict__ Wg = Wt + (size_t)s * 32 * D;
    __shared__ __align__(16) float Vi[32 * 68], Wi[32 * 68], Vj[32 * 68], Wj[32 * 68];
    const int tid = threadIdx.x, tx = tid & 15, ty = tid >> 4;
    const float4 z4 = {0.f, 0.f, 0.f, 0.f};
    for (int e = tid; e < 512; e += 256) {
        const int t = e >> 4, c4 = (e & 15) * 4;
        const int gi = i0 + c4, gj = j0 + c4;
        *(float4*)&Vi[t * 68 + c4] = (gi < D) ? *(const float4*)&Vg[t * D + gi] : z4;
        *(float4*)&Wi[t * 68 + c4] = (gi < D) ? *(const float4*)&Wg[t * D + gi] : z4;
        *(float4*)&Vj[t * 68 + c4] = (gj < D) ? *(const float4*)&Vg[t * D + gj] : z4;
        *(float4*)&Wj[t * 68 + c4] = (gj < D) ? *(const float4*)&Wg[t * D + gj] : z4;
    }
    __syncthreads();
    float acc[4][4] = {{0.f}};
#pragma unroll 4
    for (int t = 0; t < 32; t++) {
        const float4 va = *(const float4*)&Vi[t * 68 + 4 * ty];
        const float4 wa = *(const float4*)&Wi[t * 68 + 4 * ty];
        const float4 vc = *(const float4*)&Vj[t * 68 + 4 * tx];
        const float4 wc = *(const float4*)&Wj[t * 68 + 4 * tx];
        const float av[4] = {va.x, va.y, va.z, va.w};
        const float aw[4] = {wa.x, wa.y, wa.z, wa.w};
        const float bv[4] = {vc.x, vc.y, vc.z, vc.w};
        const float bw[4] = {wc.x, wc.y, wc.z, wc.w};
#pragma unroll
        for (int r = 0; r < 4; r++)
#pragma unroll
            for (int q = 0; q < 4; q++) acc[r][q] += av[r] * bw[q] + aw[r] * bv[q];
    }
    const int gj = j0 + 4 * tx;
    if (gj >= D) return;
#pragma unroll
    for (int r = 0; r < 4; r++) {
        const int gi = i0 + 4 * ty + r;
        if (gi >= D) continue;
        float4 c = *(float4*)&Ts[(size_t)gi * D + gj];
        c.x -= acc[r][0]; c.y -= acc[r][1]; c.z -= acc[r][2]; c.w -= acc[r][3];
        *(float4*)&Ts[(size_t)gi * D + gj] = c;
    }
}

// ---------------- Kernel 3: bisection v3 (rcp, 26 iters). grid (4,64) x 128 -----
__global__ __launch_bounds__(128) void bisect_kernel(const float* __restrict__ dvec,
                                                     const float* __restrict__ evec,
                                                     float* __restrict__ lam) {
    const int s = blockIdx.y, seg = blockIdx.x;
    const int tid = threadIdx.x;
    __shared__ float d[D], e2c[D], ea[D];
    __shared__ float rlo[2], rhi[2];
    for (int i = tid; i < D; i += 128) {
        d[i] = dvec[s * D + i];
        const float ev = evec[s * D + i];
        ea[i] = fabsf(ev);
        e2c[i] = fmaxf(ev * ev, 1e-34f);
    }
    __syncthreads();
    float lo = 1e30f, hi = -1e30f;
    for (int i = tid; i < D; i += 128) {
        const float rad = ea[i] + ((i > 0) ? ea[i - 1] : 0.f);
        lo = fminf(lo, d[i] - rad);
        hi = fmaxf(hi, d[i] + rad);
    }
    lo = waveMin(lo); hi = waveMax(hi);
    if ((tid & 63) == 0) { rlo[tid >> 6] = lo; rhi[tid >> 6] = hi; }
    __syncthreads();
    lo = fminf(rlo[0], rlo[1]); hi = fmaxf(rhi[0], rhi[1]);
    lo -= 1e-3f * fmaxf(fabsf(lo), 1.f);
    hi += 1e-3f * fmaxf(fabsf(hi), 1.f);
    float a = lo, b = hi;
    const int j1 = seg * 128 + tid + 1;
    for (int it = 0; it < 26; it++) {
        const float mid = 0.5f * (a + b);
        int cnt = 0;
        float q = d[0] - mid;
        cnt += (q < 0.f);
        for (int i = 1; i < D; i++) {
            q = d[i] - mid - e2c[i - 1] * __builtin_amdgcn_rcpf(q);
            cnt += (q < 0.f);
        }
        if (cnt >= j1) b = mid; else a = mid;
    }
    lam[s * D + seg * 128 + tid] = 0.5f * (a + b);
}

// ---------------- Kernel 4a: Cholesky panel (upper storage, L^T rows) -----------
__global__ __launch_bounds__(256) void chol_panel(float* __restrict__ M,
                                                  const float* __restrict__ lam,
                                                  float* __restrict__ logdet,
                                                  float* __restrict__ Lp,
                                                  int j0, int first) {
    const int s = blockIdx.x;
    float* __restrict__ Ms = M + (size_t)s * D * D;
    float* __restrict__ Lps = Lp + (size_t)s * 32 * D;
    const int tid = threadIdx.x, lane = tid & 63, wid = tid >> 6;
    extern __shared__ float smc[];
    float* __restrict__ P = smc;          // 32*520
    const int Wd = D - j0;
    for (int e = tid; e < 32 * D; e += 256) {
        const int t = e >> 9, i = e & 511;
        if (i >= j0) {
            const int il = i - j0;
            float v = Ms[(size_t)(j0 + t) * D + i];
            if (il == t) v += 0.01f * lam[s * D + j0 + t];
            P[t * 520 + il] = v;
        }
    }
    __syncthreads();
    float lacc = 0.f;
    for (int jl = 0; jl < 32; jl++) {
        const float pd = P[jl * 520 + jl];
        const float inv = 1.f / sqrtf(pd);
        if (tid == 0) { lacc += 0.5f * logf(pd); P[jl * 520 + jl] = sqrtf(pd); }
        for (int il = jl + 1 + tid; il < Wd; il += 256) P[jl * 520 + il] *= inv;
        __syncthreads();
        for (int kk = jl + 1 + wid; kk < 32; kk += 4) {
            const float f = P[jl * 520 + kk];
            for (int il = kk + lane; il < Wd; il += 64) P[kk * 520 + il] -= f * P[jl * 520 + il];
        }
        __syncthreads();
    }
    if (tid == 0) logdet[s] = (first ? 0.f : logdet[s]) + 2.f * lacc;
    for (int e = tid; e < 32 * D; e += 256) {
        const int t = e >> 9, i = e & 511;
        const int il = i - j0;
        if (il >= t) Ms[(size_t)(j0 + t) * D + i] = P[t * 520 + il];
        if (i >= j0 + 32) Lps[(size_t)t * D + i] = P[t * 520 + il];
    }
}

// ---------------- Kernel 4b: chol trailing update (rank 32) ---------------------
__global__ __launch_bounds__(256) void chol_update(float* __restrict__ M,
                                                   const float* __restrict__ Lp,
                                                   int r0) {
    if (blockIdx.x < blockIdx.y) return;
    const int s = blockIdx.z;
    const int i0 = r0 + 64 * blockIdx.y;
    const int j0 = r0 + 64 * blockIdx.x;
    float* __restrict__ Ms = M + (size_t)s * D * D;
    const float* __restrict__ Lps = Lp + (size_t)s * 32 * D;
    __shared__ __align__(16) float Li[32 * 68], Lj[32 * 68];
    const int tid = threadIdx.x, tx = tid & 15, ty = tid >> 4;
    const float4 z4 = {0.f, 0.f, 0.f, 0.f};
    for (int e = tid; e < 512; e += 256) {
        const int t = e >> 4, c4 = (e & 15) * 4;
        const int gi = i0 + c4, gj = j0 + c4;
        *(float4*)&Li[t * 68 + c4] = (gi < D) ? *(const float4*)&Lps[(size_t)t * D + gi] : z4;
        *(float4*)&Lj[t * 68 + c4] = (gj < D) ? *(const float4*)&Lps[(size_t)t * D + gj] : z4;
    }
    __syncthreads();
    float acc[4][4] = {{0.f}};
#pragma unroll 4
    for (int t = 0; t < 32; t++) {
        const float4 a = *(const float4*)&Li[t * 68 + 4 * ty];
        const float4 b = *(const float4*)&Lj[t * 68 + 4 * tx];
        const float av[4] = {a.x, a.y, a.z, a.w};
        const float bv[4] = {b.x, b.y, b.z, b.w};
#pragma unroll
        for (int r = 0; r < 4; r++)
#pragma unroll
            for (int q = 0; q < 4; q++) acc[r][q] += av[r] * bv[q];
    }
    const int gj = j0 + 4 * tx;
    if (gj >= D) return;
#pragma unroll
    for (int r = 0; r < 4; r++) {
        const int gi = i0 + 4 * ty + r;
        if (gi >= D) continue;
        float4 c = *(float4*)&Ms[(size_t)gi * D + gj];
        c.x -= acc[r][0]; c.y -= acc[r][1]; c.z -= acc[r][2]; c.w -= acc[r][3];
        *(float4*)&Ms[(size_t)gi * D + gj] = c;
    }
}

// ---------------- Kernel 5: invert 64x64 diagonal blocks of L (L stored ^T) -----
__global__ __launch_bounds__(64) void invdiag_kernel(const float* __restrict__ M,
                                                     float* __restrict__ invDT) {
    const int b = blockIdx.x, s = b >> 3, I = b & 7;
    const int c = threadIdx.x;
    __shared__ float Lsh[64 * 65];
    __shared__ float xsh[64 * 65];
    const float* __restrict__ Ms = M + (size_t)s * D * D;
    for (int e = c; e < 4096; e += 64) {
        const int i = e & 63, k = e >> 6;
        Lsh[i * 65 + k] = Ms[(size_t)(I * 64 + k) * D + I * 64 + i];
    }
    for (int i = 0; i < 64; i++) xsh[c * 65 + i] = (i == c) ? 1.f : 0.f;
    __syncthreads();
    for (int i = 0; i < 64; i++) {
        float t = xsh[c * 65 + i];
        for (int k = 0; k < i; k++) t -= Lsh[i * 65 + k] * xsh[c * 65 + k];
        xsh[c * 65 + i] = t / Lsh[i * 65 + i];
    }
    float* __restrict__ outp = invDT + (size_t)b * 4096 + c * 64;
    for (int i = 0; i < 64; i++) outp[i] = xsh[c * 65 + i];  // invDT[b][c][i] = invL[i][c]
}

// ---------------- Kernel 5b: triangular inverse step ----------------------------
__global__ __launch_bounds__(256) void triinv_step(float* __restrict__ M,
                                                   const float* __restrict__ invDT,
                                                   int I) {
    const int J = blockIdx.x, s = blockIdx.y;
    float* __restrict__ Ms = M + (size_t)s * D * D;
    __shared__ __align__(16) float Ls[64 * 68];
    __shared__ __align__(16) float Bs[64 * 68];
    __shared__ __align__(16) float Ss[64 * 68];
    const int tid = threadIdx.x, tx = tid & 15, ty = tid >> 4;
    float acc[4][4] = {{0.f}};
    for (int K = J; K < I; K++) {
        __syncthreads();
        for (int e = tid; e < 4096; e += 256) {
            const int k = e >> 6, r = e & 63;
            Ls[k * 68 + r] = Ms[(size_t)(K * 64 + k) * D + I * 64 + r];
        }
        if (K == J) {
            const float* __restrict__ dJ = invDT + ((size_t)s * 8 + J) * 4096;
            for (int e = tid; e < 4096; e += 256) {
                const int c = e >> 6, k = e & 63;
                Bs[k * 68 + c] = dJ[c * 64 + k];
            }
        } else {
            for (int e = tid; e < 4096; e += 256) {
                const int k = e >> 6, c = e & 63;
                Bs[k * 68 + c] = Ms[(size_t)(K * 64 + k) * D + J * 64 + c];
            }
        }
        __syncthreads();
#pragma unroll 4
        for (int k = 0; k < 64; k++) {
            const float4 a = *(const float4*)&Ls[k * 68 + 4 * ty];
            const float4 b = *(const float4*)&Bs[k * 68 + 4 * tx];
            const float av[4] = {a.x, a.y, a.z, a.w};
            const float bv[4] = {b.x, b.y, b.z, b.w};
#pragma unroll
            for (int r = 0; r < 4; r++)
#pragma unroll
                for (int q = 0; q < 4; q++) acc[r][q] += av[r] * bv[q];
        }
    }
    __syncthreads();
#pragma unroll
    for (int r = 0; r < 4; r++) {
        float4 v4;
        v4.x = acc[r][0]; v4.y = acc[r][1]; v4.z = acc[r][2]; v4.w = acc[r][3];
        *(float4*)&Ss[(4 * ty + r) * 68 + 4 * tx] = v4;
    }
    {
        const float* __restrict__ dI = invDT + ((size_t)s * 8 + I) * 4096;
        for (int e = tid; e < 4096; e += 256) {
            const int k = e >> 6, r = e & 63;
            Ls[k * 68 + r] = dI[k * 64 + r];
        }
    }
    __syncthreads();
    float o[4][4] = {{0.f}};
#pragma unroll 4
    for (int k = 0; k < 64; k++) {
        const float4 a = *(const float4*)&Ls[k * 68 + 4 * ty];
        const float4 b = *(const float4*)&Ss[k * 68 + 4 * tx];
        const float av[4] = {a.x, a.y, a.z, a.w};
        const float bv[4] = {b.x, b.y, b.z, b.w};
#pragma unroll
        for (int r = 0; r < 4; r++)
#pragma unroll
            for (int q = 0; q < 4; q++) o[r][q] += av[r] * bv[q];
    }
#pragma unroll
    for (int r = 0; r < 4; r++) {
        float4 v4;
        v4.x = -o[r][0]; v4.y = -o[r][1]; v4.z = -o[r][2]; v4.w = -o[r][3];
        *(float4*)&Ms[(size_t)(I * 64 + 4 * ty + r) * D + J * 64 + 4 * tx] = v4;
    }
}

// ---------------- Kernel 6: fused GEMM + mahalanobis ----------------------------
__global__ __launch_bounds__(256) void gemm_maha(const float* __restrict__ M,
                                                 const float* __restrict__ invDT,
                                                 const float* __restrict__ xT,
                                                 const float* __restrict__ mu,
                                                 const float* __restrict__ logdet,
                                                 float* __restrict__ out) {
    const int s = blockIdx.y;
    const int n0 = blockIdx.x * 64;
    const int tid = threadIdx.x, tx = tid & 15, ty = tid >> 4;
    const float* __restrict__ Ms = M + (size_t)s * D * D;
    const float* __restrict__ mus = mu + s * D;
    __shared__ __align__(16) float As[32 * 136];
    __shared__ __align__(16) float Bs[32 * 68];
    __shared__ float red[16 * 68];
    float cs[4] = {0.f, 0.f, 0.f, 0.f};

    for (int ci = 0; ci < 4; ci++) {
        const int i0 = ci * 128;
        float acc[8][4];
#pragma unroll
        for (int r = 0; r < 8; r++)
#pragma unroll
            for (int q = 0; q < 4; q++) acc[r][q] = 0.f;
        const int nkc = (ci + 1) * 4;
        for (int kc = 0; kc < nkc; kc++) {
            const int k0 = kc * 32, kb = k0 >> 6;
            __syncthreads();
            for (int e = tid; e < 4096; e += 256) {
                const int il = e >> 5, kk = e & 31;
                const int ib = (i0 + il) >> 6;
                As[kk * 136 + il] = (kb < ib) ? Ms[(size_t)(i0 + il) * D + k0 + kk] : 0.f;
            }
            if (kb >= 2 * ci) {
                const float* __restrict__ dB = invDT + ((size_t)s * 8 + kb) * 4096
                                             + (size_t)(k0 & 63) * 64;
                const int ilb = (kb - 2 * ci) * 64;
                for (int e = tid; e < 2048; e += 256) {
                    const int ii = e & 63, kk = e >> 6;
                    As[kk * 136 + ilb + ii] = dB[kk * 64 + ii];
                }
            }
            for (int e = tid; e < 2048; e += 256) {
                const int nn = e & 63, kk = e >> 6;
                Bs[kk * 68 + nn] = xT[(size_t)(k0 + kk) * 2048 + n0 + nn] - mus[k0 + kk];
            }
            __syncthreads();
#pragma unroll 8
            for (int kk = 0; kk < 32; kk++) {
                const float4 a0 = *(const float4*)&As[kk * 136 + 8 * ty];
                const float4 a1 = *(const float4*)&As[kk * 136 + 8 * ty + 4];
                const float4 b  = *(const float4*)&Bs[kk * 68 + 4 * tx];
                const float av[8] = {a0.x, a0.y, a0.z, a0.w, a1.x, a1.y, a1.z, a1.w};
                const float bv[4] = {b.x, b.y, b.z, b.w};
#pragma unroll
                for (int r = 0; r < 8; r++)
#pragma unroll
                    for (int q = 0; q < 4; q++) acc[r][q] += av[r] * bv[q];
            }
        }
#pragma unroll
        for (int r = 0; r < 8; r++)
#pragma unroll
            for (int q = 0; q < 4; q++) cs[q] += acc[r][q] * acc[r][q];
    }
    __syncthreads();
#pragma unroll
    for (int q = 0; q < 4; q++) red[ty * 68 + 4 * tx + q] = cs[q];
    __syncthreads();
    if (tid < 64) {
        float mah = 0.f;
#pragma unroll
        for (int t = 0; t < 16; t++) mah += red[t * 68 + tid];
        out[(size_t)(n0 + tid) * 64 + s] = -0.5f * (mah + logdet[s] + 940.993058f);
    }
}

extern "C" void kernel_launch(void* const* d_in, const int* in_sizes, int n_in,
                              void* d_out, int out_size, void* d_ws, size_t ws_size,
                              hipStream_t stream) {
    const float* x  = (const float*)d_in[0];   // (2048, 512)
    const float* mu = (const float*)d_in[1];   // (64, 1, 512)
    const float* sp = (const float*)d_in[3];   // (64, 1, 512, 512)
    float* out = (float*)d_out;                // (2048, 64) fp32

    float* wsf  = (float*)d_ws;
    float* MT   = wsf;                          // 16,777,216 floats
    float* dvec = wsf + (size_t)16777216;       // 32768
    float* evec = dvec + 32768;
    float* lamv = evec + 32768;
    float* logd = lamv + 32768;                 // 64
    float* Vt   = logd + 64;                    // 1,048,576
    float* Wt   = Vt + (size_t)1048576;         // 1,048,576
    float* xT   = Wt + (size_t)1048576;         // 1,048,576
    float* Lp   = Vt;                           // reuse (chol after tridiag)
    float* invDT = Vt;                          // reuse (after chol)

    // 0) transpose x; 1) m = A^T A
    xpose_kernel<<<dim3(32, 8), dim3(256), 0, stream>>>(x, xT);
    syrk_kernel<<<dim3(64, 64), dim3(256), 0, stream>>>(sp, MT);

    // 2) blocked LATRD tridiagonalization
    const size_t plds = (size_t)34900 * sizeof(float);
    for (int p = 0; p < 16; p++) {
        const int ps = 32 * p;
        const int jmax = (p == 15) ? 30 : 32;
        latrd_panel<<<dim3(64), dim3(1024), plds, stream>>>(MT, Vt, Wt, dvec, evec, ps, jmax);
        if (p < 15) {
            const int r0 = ps + 32;
            const int nt = (D - r0 + 63) / 64;
            latrd_update<<<dim3(nt, nt, 64), dim3(256), 0, stream>>>(MT, Vt, Wt, r0);
        }
    }

    // 3) all eigenvalues via Sturm bisection (rcp-based)
    bisect_kernel<<<dim3(4, 64), dim3(128), 0, stream>>>(dvec, evec, lamv);

    // 4) rebuild m, then blocked Cholesky of sigma (L stored transposed in upper)
    syrk_kernel<<<dim3(64, 64), dim3(256), 0, stream>>>(sp, MT);
    const size_t clds = (size_t)(32 * 520 + 4) * sizeof(float);
    for (int p = 0; p < 16; p++) {
        const int j0 = 32 * p;
        chol_panel<<<dim3(64), dim3(256), clds, stream>>>(MT, lamv, logd, Lp, j0, p == 0 ? 1 : 0);
        if (p < 15) {
            const int r0 = j0 + 32;
            const int nt = (D - r0 + 63) / 64;
            chol_update<<<dim3(nt, nt, 64), dim3(256), 0, stream>>>(MT, Lp, r0);
        }
    }

    // 5) full triangular inverse: diag blocks, then off-diag into MT lower
    invdiag_kernel<<<dim3(512), dim3(64), 0, stream>>>(MT, invDT);
    for (int I = 1; I < 8; I++)
        triinv_step<<<dim3(I, 64), dim3(256), 0, stream>>>(MT, invDT, I);

    // 6) fused GEMM + mahalanobis + epilogue
    gemm_maha<<<dim3(32, 64), dim3(256), 0, stream>>>(MT, invDT, xT, mu, logd, out);
}

// Round 7
// 9739.226 us; speedup vs baseline: 1.2412x; 1.2412x over previous
//
#include <hip/hip_runtime.h>

#define D 512
#define TW 16

__device__ __forceinline__ float waveSum(float v) {
#pragma unroll
    for (int m = 32; m > 0; m >>= 1) v += __shfl_xor(v, m, 64);
    return v;
}
__device__ __forceinline__ float waveMin(float v) {
#pragma unroll
    for (int m = 32; m > 0; m >>= 1) v = fminf(v, __shfl_xor(v, m, 64));
    return v;
}
__device__ __forceinline__ float waveMax(float v) {
#pragma unroll
    for (int m = 32; m > 0; m >>= 1) v = fmaxf(v, __shfl_xor(v, m, 64));
    return v;
}

// ---------------- Kernel 0: xT[d][n] = x[n][d]. grid (32, 8), 256 thr ----------
__global__ __launch_bounds__(256) void xpose_kernel(const float* __restrict__ x,
                                                    float* __restrict__ xT) {
    __shared__ float t[64][65];
    const int bx = blockIdx.x * 64;  // n block
    const int by = blockIdx.y * 64;  // d block
    const int tid = threadIdx.x;
    const int lx = tid & 63, lq = tid >> 6;
#pragma unroll
    for (int r = 0; r < 64; r += 4)
        t[r + lq][lx] = x[(size_t)(bx + r + lq) * D + by + lx];
    __syncthreads();
#pragma unroll
    for (int r = 0; r < 64; r += 4)
        xT[(size_t)(by + r + lq) * 2048 + bx + lx] = t[lx][r + lq];
}

// ---------------- Kernel 1: m = A^T A (per s). grid (64 tiles, 64 s), 256 thr ----
__global__ __launch_bounds__(256) void syrk_kernel(const float* __restrict__ sp,
                                                   float* __restrict__ M) {
    const int s = blockIdx.y;
    const int I = blockIdx.x >> 3, J = blockIdx.x & 7;
    const int tx = threadIdx.x & 15, ty = threadIdx.x >> 4;
    const float* __restrict__ A = sp + (size_t)s * D * D;
    __shared__ __align__(16) float As[64 * 68];
    __shared__ __align__(16) float Bs[64 * 68];
    float acc[4][4];
#pragma unroll
    for (int r = 0; r < 4; r++)
#pragma unroll
        for (int q = 0; q < 4; q++) acc[r][q] = 0.f;

    for (int k0 = 0; k0 < D; k0 += 64) {
        for (int e = threadIdx.x; e < 4096; e += 256) {
            const int col = e & 63, kr = e >> 6;
            As[kr * 68 + col] = A[(size_t)(k0 + kr) * D + I * 64 + col];
            Bs[kr * 68 + col] = A[(size_t)(k0 + kr) * D + J * 64 + col];
        }
        __syncthreads();
#pragma unroll 4
        for (int k = 0; k < 64; k++) {
            const float4 a = *(const float4*)&As[k * 68 + 4 * ty];
            const float4 b = *(const float4*)&Bs[k * 68 + 4 * tx];
            const float av[4] = {a.x, a.y, a.z, a.w};
            const float bv[4] = {b.x, b.y, b.z, b.w};
#pragma unroll
            for (int r = 0; r < 4; r++)
#pragma unroll
                for (int q = 0; q < 4; q++) acc[r][q] += av[r] * bv[q];
        }
        __syncthreads();
    }
#pragma unroll
    for (int r = 0; r < 4; r++) {
        float4 v4;
        v4.x = acc[r][0]; v4.y = acc[r][1]; v4.z = acc[r][2]; v4.w = acc[r][3];
        const size_t off = (size_t)s * D * D + (size_t)(I * 64 + 4 * ty + r) * D + J * 64 + 4 * tx;
        *(float4*)(M + off) = v4;
    }
}

// ---------------- Kernel 2a: LATRD panel v4. 64 WGs x 1024 thr ------------------
// 4 barriers/column: pv computed via identity v^T p = beta*(v^T A v - 2*c1.c2),
// with v^T A v partials folded into the symv reduction. Vs/Ws stride 34 (float2).
__global__ __launch_bounds__(1024) void latrd_panel(float* __restrict__ T,
                                                    float* __restrict__ Vt,
                                                    float* __restrict__ Wt,
                                                    float* __restrict__ dvec,
                                                    float* __restrict__ evec,
                                                    int ps, int jmax) {
    const int s = blockIdx.x;
    float* __restrict__ Ts = T + (size_t)s * D * D;
    float* __restrict__ Vg = Vt + (size_t)s * 32 * D;
    float* __restrict__ Wg = Wt + (size_t)s * 32 * D;
    const int tid = threadIdx.x, lane = tid & 63, wid = tid >> 6;
    const int l4 = lane & 15, quad = lane >> 4;
    extern __shared__ float sm[];
    float* __restrict__ Vs = sm;              // 512*34
    float* __restrict__ Ws = sm + 17408;      // 512*34
    float* __restrict__ vb = sm + 34816;      // 512
    float* __restrict__ pf = sm + 35328;      // 512
    float* __restrict__ c1 = sm + 35840;      // 32
    float* __restrict__ c2 = sm + 35872;      // 32
    float* __restrict__ red = sm + 35904;     // 16
    float* __restrict__ sca = sm + 35920;     // 4

    for (int i = tid; i < 35328; i += 1024) sm[i] = 0.f;  // Vs, Ws, vb
    __syncthreads();

    float rk = (tid < D) ? Ts[(size_t)ps * D + tid] : 0.f;

    for (int j = 0; j < jmax; j++) {
        const int k = ps + j, sup = k + 1;
        // ---- S1: corrected pivot row -> vb (cols >= j of Vs/Ws are zero) ----
        float val = 0.f;
        if (tid < D && tid > k) {
            const float* __restrict__ vrow = Vs + tid * 34;
            const float* __restrict__ wrow = Ws + tid * 34;
            const float* __restrict__ vk = Vs + k * 34;
            const float* __restrict__ wk = Ws + k * 34;
            float corr = 0.f;
#pragma unroll
            for (int t = 0; t < 32; t += 2) {
                const float2 a  = *(const float2*)&vrow[t];
                const float2 bw = *(const float2*)&wk[t];
                const float2 aw = *(const float2*)&wrow[t];
                const float2 bv = *(const float2*)&vk[t];
                corr += a.x * bw.x + a.y * bw.y + aw.x * bv.x + aw.y * bv.y;
            }
            val = rk - corr;
            vb[tid] = val;
            if (tid == sup) sca[3] = val;  // a0
        } else if (tid == k) {
            const float* __restrict__ vk = Vs + k * 34;
            const float* __restrict__ wk = Ws + k * 34;
            float dc = 0.f;
            for (int t = 0; t < 32; t++) dc += vk[t] * wk[t];
            dvec[s * D + k] = rk - 2.f * dc;
            vb[k] = 0.f;
        }
        float xp = (tid < D && tid > sup) ? val * val : 0.f;
        xp = waveSum(xp);
        if (lane == 0) red[wid] = xp;
        __syncthreads();                                   // B1

        // ---- S2: all threads: xn2, beta, v0; 32-groups: c1/c2 ----
        float xn2 = 0.f;
#pragma unroll
        for (int q = 0; q < TW; q++) xn2 += red[q];
        const float a0 = sca[3];
        const int skip = (xn2 <= 0.f);
        float beta = 0.f, v0 = 0.f, alpha = a0;
        if (!skip) {
            const float an = sqrtf(a0 * a0 + xn2);
            alpha = (a0 >= 0.f) ? -an : an;
            v0 = a0 - alpha;
            beta = 2.f / (v0 * v0 + xn2);
        }
        if (tid == sup) {
            evec[s * D + k] = skip ? a0 : alpha;
            if (!skip) vb[sup] = v0;
        }
        if (!skip) {
            const int t = tid >> 5, r = tid & 31;
            float a1 = 0.f, a2 = 0.f;
            for (int i = sup + 1 + r; i < D; i += 32) {
                const float v = vb[i];
                a1 += Ws[i * 34 + t] * v;
                a2 += Vs[i * 34 + t] * v;
            }
#pragma unroll
            for (int m = 16; m > 0; m >>= 1) {
                a1 += __shfl_xor(a1, m, 64);
                a2 += __shfl_xor(a2, m, 64);
            }
            if (r == 0) {
                c1[t] = a1 + Ws[sup * 34 + t] * v0;
                c2[t] = a2 + Vs[sup * 34 + t] * v0;
            }
        }
        __syncthreads();                                   // B2
        if (skip) {
            if (tid < D && tid >= sup) { Vg[j * D + tid] = 0.f; Wg[j * D + tid] = 0.f; }
            if (tid < D && k + 1 < D) rk = Ts[(size_t)(k + 1) * D + tid];
            __syncthreads();
            continue;
        }
        // c12 = c1 . c2 (all threads redundantly; c1/c2 final after B2)
        float c12 = 0.f;
#pragma unroll
        for (int t = 0; t < 32; t += 4) {
            const float4 ca = *(const float4*)&c1[t];
            const float4 cb = *(const float4*)&c2[t];
            c12 += ca.x * cb.x + ca.y * cb.y + ca.z * cb.z + ca.w * cb.w;
        }

        // ---- S3: symv quarter-wave; fold v^T A v partials; pf = corrected/unscaled
        const int w0 = sup & ~63;
        float vAvp = 0.f;
        for (int i = sup + (wid * 4 + quad); i < D; i += 64) {
            const float* __restrict__ row = Ts + (size_t)i * D;
            float4 a4 = {0.f, 0.f, 0.f, 0.f};
            for (int c = w0 + 4 * l4; c < D; c += 64) {
                const float4 a = *(const float4*)&row[c];
                const float4 b = *(const float4*)&vb[c];
                a4.x += a.x * b.x; a4.y += a.y * b.y;
                a4.z += a.z * b.z; a4.w += a.w * b.w;
            }
            const float raw = (a4.x + a4.y) + (a4.z + a4.w);
            vAvp += vb[i] * raw;
            float t1 = raw
                - (Vs[i * 34 + l4] * c1[l4] + Vs[i * 34 + l4 + 16] * c1[l4 + 16]
                 + Ws[i * 34 + l4] * c2[l4] + Ws[i * 34 + l4 + 16] * c2[l4 + 16]);
#pragma unroll
            for (int m = 1; m < 16; m <<= 1) t1 += __shfl_xor(t1, m, 64);
            if (l4 == 0) pf[i] = t1;
        }
        vAvp = waveSum(vAvp);
        if (lane == 0) red[wid] = vAvp;
        __syncthreads();                                   // B3

        // ---- S5: pv identity; w = beta*pf - cc*v; store V/W; prefetch ----
        float vAv = 0.f;
#pragma unroll
        for (int q = 0; q < TW; q++) vAv += red[q];
        const float cc = 0.5f * beta * beta * (vAv - 2.f * c12);
        if (tid < D) {
            if (tid >= sup) {
                const float v = vb[tid];
                const float w = beta * pf[tid] - cc * v;
                Vs[tid * 34 + j] = v;
                Ws[tid * 34 + j] = w;
                Vg[j * D + tid] = v;
                Wg[j * D + tid] = w;
            }
            if (k + 1 < D) rk = Ts[(size_t)(k + 1) * D + tid];
        }
        __syncthreads();                                   // B4
    }
    if (ps + jmax == D - 2 && tid == 0) {
        const int k1 = D - 2, k2 = D - 1;
        float dc = 0.f, ec = 0.f, dc2 = 0.f;
        for (int t = 0; t < jmax; t++) {
            dc  += Vs[k1 * 34 + t] * Ws[k1 * 34 + t];
            ec  += Vs[k1 * 34 + t] * Ws[k2 * 34 + t]
                 + Ws[k1 * 34 + t] * Vs[k2 * 34 + t];
            dc2 += Vs[k2 * 34 + t] * Ws[k2 * 34 + t];
        }
        dvec[s * D + k1] = Ts[(size_t)k1 * D + k1] - 2.f * dc;
        evec[s * D + k1] = Ts[(size_t)k1 * D + k2] - ec;
        dvec[s * D + k2] = Ts[(size_t)k2 * D + k2] - 2.f * dc2;
        evec[s * D + k2] = 0.f;
    }
}

// ---------------- Kernel 2b: rank-64 symmetric update A -= V W^T + W V^T --------
__global__ __launch_bounds__(256) void latrd_update(float* __restrict__ T,
                                                    const float* __restrict__ Vt,
                                                    const float* __restrict__ Wt,
                                                    int r0) {
    const int s = blockIdx.z;
    const int i0 = r0 + 64 * blockIdx.y;
    const int j0 = r0 + 64 * blockIdx.x;
    float* __restrict__ Ts = T + (size_t)s * D * D;
    const float* __restrict__ Vg = Vt + (size_t)s * 32 * D;
    const float* __restrict__ Wg = Wt + (size_t)s * 32 * D;
    __shared__ __align__(16) float Vi[32 * 68], Wi[32 * 68], Vj[32 * 68], Wj[32 * 68];
    const int tid = threadIdx.x, tx = tid & 15, ty = tid >> 4;
    const float4 z4 = {0.f, 0.f, 0.f, 0.f};
    for (int e = tid; e < 512; e += 256) {
        const int t = e >> 4, c4 = (e & 15) * 4;
        const int gi = i0 + c4, gj = j0 + c4;
        *(float4*)&Vi[t * 68 + c4] = (gi < D) ? *(const float4*)&Vg[t * D + gi] : z4;
        *(float4*)&Wi[t * 68 + c4] = (gi < D) ? *(const float4*)&Wg[t * D + gi] : z4;
        *(float4*)&Vj[t * 68 + c4] = (gj < D) ? *(const float4*)&Vg[t * D + gj] : z4;
        *(float4*)&Wj[t * 68 + c4] = (gj < D) ? *(const float4*)&Wg[t * D + gj] : z4;
    }
    __syncthreads();
    float acc[4][4] = {{0.f}};
#pragma unroll 4
    for (int t = 0; t < 32; t++) {
        const float4 va = *(const float4*)&Vi[t * 68 + 4 * ty];
        const float4 wa = *(const float4*)&Wi[t * 68 + 4 * ty];
        const float4 vc = *(const float4*)&Vj[t * 68 + 4 * tx];
        const float4 wc = *(const float4*)&Wj[t * 68 + 4 * tx];
        const float av[4] = {va.x, va.y, va.z, va.w};
        const float aw[4] = {wa.x, wa.y, wa.z, wa.w};
        const float bv[4] = {vc.x, vc.y, vc.z, vc.w};
        const float bw[4] = {wc.x, wc.y, wc.z, wc.w};
#pragma unroll
        for (int r = 0; r < 4; r++)
#pragma unroll
            for (int q = 0; q < 4; q++) acc[r][q] += av[r] * bw[q] + aw[r] * bv[q];
    }
    const int gj = j0 + 4 * tx;
    if (gj >= D) return;
#pragma unroll
    for (int r = 0; r < 4; r++) {
        const int gi = i0 + 4 * ty + r;
        if (gi >= D) continue;
        float4 c = *(float4*)&Ts[(size_t)gi * D + gj];
        c.x -= acc[r][0]; c.y -= acc[r][1]; c.z -= acc[r][2]; c.w -= acc[r][3];
        *(float4*)&Ts[(size_t)gi * D + gj] = c;
    }
}

// ---------------- Kernel 3: bisection v3 (rcp, 26 iters). grid (4,64) x 128 -----
__global__ __launch_bounds__(128) void bisect_kernel(const float* __restrict__ dvec,
                                                     const float* __restrict__ evec,
                                                     float* __restrict__ lam) {
    const int s = blockIdx.y, seg = blockIdx.x;
    const int tid = threadIdx.x;
    __shared__ float d[D], e2c[D], ea[D];
    __shared__ float rlo[2], rhi[2];
    for (int i = tid; i < D; i += 128) {
        d[i] = dvec[s * D + i];
        const float ev = evec[s * D + i];
        ea[i] = fabsf(ev);
        e2c[i] = fmaxf(ev * ev, 1e-34f);
    }
    __syncthreads();
    float lo = 1e30f, hi = -1e30f;
    for (int i = tid; i < D; i += 128) {
        const float rad = ea[i] + ((i > 0) ? ea[i - 1] : 0.f);
        lo = fminf(lo, d[i] - rad);
        hi = fmaxf(hi, d[i] + rad);
    }
    lo = waveMin(lo); hi = waveMax(hi);
    if ((tid & 63) == 0) { rlo[tid >> 6] = lo; rhi[tid >> 6] = hi; }
    __syncthreads();
    lo = fminf(rlo[0], rlo[1]); hi = fmaxf(rhi[0], rhi[1]);
    lo -= 1e-3f * fmaxf(fabsf(lo), 1.f);
    hi += 1e-3f * fmaxf(fabsf(hi), 1.f);
    float a = lo, b = hi;
    const int j1 = seg * 128 + tid + 1;
    for (int it = 0; it < 26; it++) {
        const float mid = 0.5f * (a + b);
        int cnt = 0;
        float q = d[0] - mid;
        cnt += (q < 0.f);
        for (int i = 1; i < D; i++) {
            q = d[i] - mid - e2c[i - 1] * __builtin_amdgcn_rcpf(q);
            cnt += (q < 0.f);
        }
        if (cnt >= j1) b = mid; else a = mid;
    }
    lam[s * D + seg * 128 + tid] = 0.5f * (a + b);
}

// ---------------- Kernel 4a: Cholesky panel (upper storage, L^T rows) -----------
__global__ __launch_bounds__(256) void chol_panel(float* __restrict__ M,
                                                  const float* __restrict__ lam,
                                                  float* __restrict__ logdet,
                                                  float* __restrict__ Lp,
                                                  int j0, int first) {
    const int s = blockIdx.x;
    float* __restrict__ Ms = M + (size_t)s * D * D;
    float* __restrict__ Lps = Lp + (size_t)s * 32 * D;
    const int tid = threadIdx.x, lane = tid & 63, wid = tid >> 6;
    extern __shared__ float smc[];
    float* __restrict__ P = smc;          // 32*520
    const int Wd = D - j0;
    for (int e = tid; e < 32 * D; e += 256) {
        const int t = e >> 9, i = e & 511;
        if (i >= j0) {
            const int il = i - j0;
            float v = Ms[(size_t)(j0 + t) * D + i];
            if (il == t) v += 0.01f * lam[s * D + j0 + t];
            P[t * 520 + il] = v;
        }
    }
    __syncthreads();
    float lacc = 0.f;
    for (int jl = 0; jl < 32; jl++) {
        const float pd = P[jl * 520 + jl];
        const float inv = 1.f / sqrtf(pd);
        if (tid == 0) { lacc += 0.5f * logf(pd); P[jl * 520 + jl] = sqrtf(pd); }
        for (int il = jl + 1 + tid; il < Wd; il += 256) P[jl * 520 + il] *= inv;
        __syncthreads();
        for (int kk = jl + 1 + wid; kk < 32; kk += 4) {
            const float f = P[jl * 520 + kk];
            for (int il = kk + lane; il < Wd; il += 64) P[kk * 520 + il] -= f * P[jl * 520 + il];
        }
        __syncthreads();
    }
    if (tid == 0) logdet[s] = (first ? 0.f : logdet[s]) + 2.f * lacc;
    for (int e = tid; e < 32 * D; e += 256) {
        const int t = e >> 9, i = e & 511;
        const int il = i - j0;
        if (il >= t) Ms[(size_t)(j0 + t) * D + i] = P[t * 520 + il];
        if (i >= j0 + 32) Lps[(size_t)t * D + i] = P[t * 520 + il];
    }
}

// ---------------- Kernel 4b: chol trailing update (rank 32) ---------------------
__global__ __launch_bounds__(256) void chol_update(float* __restrict__ M,
                                                   const float* __restrict__ Lp,
                                                   int r0) {
    if (blockIdx.x < blockIdx.y) return;
    const int s = blockIdx.z;
    const int i0 = r0 + 64 * blockIdx.y;
    const int j0 = r0 + 64 * blockIdx.x;
    float* __restrict__ Ms = M + (size_t)s * D * D;
    const float* __restrict__ Lps = Lp + (size_t)s * 32 * D;
    __shared__ __align__(16) float Li[32 * 68], Lj[32 * 68];
    const int tid = threadIdx.x, tx = tid & 15, ty = tid >> 4;
    const float4 z4 = {0.f, 0.f, 0.f, 0.f};
    for (int e = tid; e < 512; e += 256) {
        const int t = e >> 4, c4 = (e & 15) * 4;
        const int gi = i0 + c4, gj = j0 + c4;
        *(float4*)&Li[t * 68 + c4] = (gi < D) ? *(const float4*)&Lps[(size_t)t * D + gi] : z4;
        *(float4*)&Lj[t * 68 + c4] = (gj < D) ? *(const float4*)&Lps[(size_t)t * D + gj] : z4;
    }
    __syncthreads();
    float acc[4][4] = {{0.f}};
#pragma unroll 4
    for (int t = 0; t < 32; t++) {
        const float4 a = *(const float4*)&Li[t * 68 + 4 * ty];
        const float4 b = *(const float4*)&Lj[t * 68 + 4 * tx];
        const float av[4] = {a.x, a.y, a.z, a.w};
        const float bv[4] = {b.x, b.y, b.z, b.w};
#pragma unroll
        for (int r = 0; r < 4; r++)
#pragma unroll
            for (int q = 0; q < 4; q++) acc[r][q] += av[r] * bv[q];
    }
    const int gj = j0 + 4 * tx;
    if (gj >= D) return;
#pragma unroll
    for (int r = 0; r < 4; r++) {
        const int gi = i0 + 4 * ty + r;
        if (gi >= D) continue;
        float4 c = *(float4*)&Ms[(size_t)gi * D + gj];
        c.x -= acc[r][0]; c.y -= acc[r][1]; c.z -= acc[r][2]; c.w -= acc[r][3];
        *(float4*)&Ms[(size_t)gi * D + gj] = c;
    }
}

// ---------------- Kernel 5: invert 64x64 diagonal blocks of L (L stored ^T) -----
__global__ __launch_bounds__(64) void invdiag_kernel(const float* __restrict__ M,
                                                     float* __restrict__ invDT) {
    const int b = blockIdx.x, s = b >> 3, I = b & 7;
    const int c = threadIdx.x;
    __shared__ float Lsh[64 * 65];
    __shared__ float xsh[64 * 65];
    const float* __restrict__ Ms = M + (size_t)s * D * D;
    for (int e = c; e < 4096; e += 64) {
        const int i = e & 63, k = e >> 6;
        Lsh[i * 65 + k] = Ms[(size_t)(I * 64 + k) * D + I * 64 + i];
    }
    for (int i = 0; i < 64; i++) xsh[c * 65 + i] = (i == c) ? 1.f : 0.f;
    __syncthreads();
    for (int i = 0; i < 64; i++) {
        float t = xsh[c * 65 + i];
        for (int k = 0; k < i; k++) t -= Lsh[i * 65 + k] * xsh[c * 65 + k];
        xsh[c * 65 + i] = t / Lsh[i * 65 + i];
    }
    float* __restrict__ outp = invDT + (size_t)b * 4096 + c * 64;
    for (int i = 0; i < 64; i++) outp[i] = xsh[c * 65 + i];  // invDT[b][c][i] = invL[i][c]
}

// ---------------- Kernel 5b: triangular inverse step ----------------------------
__global__ __launch_bounds__(256) void triinv_step(float* __restrict__ M,
                                                   const float* __restrict__ invDT,
                                                   int I) {
    const int J = blockIdx.x, s = blockIdx.y;
    float* __restrict__ Ms = M + (size_t)s * D * D;
    __shared__ __align__(16) float Ls[64 * 68];
    __shared__ __align__(16) float Bs[64 * 68];
    __shared__ __align__(16) float Ss[64 * 68];
    const int tid = threadIdx.x, tx = tid & 15, ty = tid >> 4;
    float acc[4][4] = {{0.f}};
    for (int K = J; K < I; K++) {
        __syncthreads();
        for (int e = tid; e < 4096; e += 256) {
            const int k = e >> 6, r = e & 63;
            Ls[k * 68 + r] = Ms[(size_t)(K * 64 + k) * D + I * 64 + r];
        }
        if (K == J) {
            const float* __restrict__ dJ = invDT + ((size_t)s * 8 + J) * 4096;
            for (int e = tid; e < 4096; e += 256) {
                const int c = e >> 6, k = e & 63;
                Bs[k * 68 + c] = dJ[c * 64 + k];
            }
        } else {
            for (int e = tid; e < 4096; e += 256) {
                const int k = e >> 6, c = e & 63;
                Bs[k * 68 + c] = Ms[(size_t)(K * 64 + k) * D + J * 64 + c];
            }
        }
        __syncthreads();
#pragma unroll 4
        for (int k = 0; k < 64; k++) {
            const float4 a = *(const float4*)&Ls[k * 68 + 4 * ty];
            const float4 b = *(const float4*)&Bs[k * 68 + 4 * tx];
            const float av[4] = {a.x, a.y, a.z, a.w};
            const float bv[4] = {b.x, b.y, b.z, b.w};
#pragma unroll
            for (int r = 0; r < 4; r++)
#pragma unroll
                for (int q = 0; q < 4; q++) acc[r][q] += av[r] * bv[q];
        }
    }
    __syncthreads();
#pragma unroll
    for (int r = 0; r < 4; r++) {
        float4 v4;
        v4.x = acc[r][0]; v4.y = acc[r][1]; v4.z = acc[r][2]; v4.w = acc[r][3];
        *(float4*)&Ss[(4 * ty + r) * 68 + 4 * tx] = v4;
    }
    {
        const float* __restrict__ dI = invDT + ((size_t)s * 8 + I) * 4096;
        for (int e = tid; e < 4096; e += 256) {
            const int k = e >> 6, r = e & 63;
            Ls[k * 68 + r] = dI[k * 64 + r];
        }
    }
    __syncthreads();
    float o[4][4] = {{0.f}};
#pragma unroll 4
    for (int k = 0; k < 64; k++) {
        const float4 a = *(const float4*)&Ls[k * 68 + 4 * ty];
        const float4 b = *(const float4*)&Ss[k * 68 + 4 * tx];
        const float av[4] = {a.x, a.y, a.z, a.w};
        const float bv[4] = {b.x, b.y, b.z, b.w};
#pragma unroll
        for (int r = 0; r < 4; r++)
#pragma unroll
            for (int q = 0; q < 4; q++) o[r][q] += av[r] * bv[q];
    }
#pragma unroll
    for (int r = 0; r < 4; r++) {
        float4 v4;
        v4.x = -o[r][0]; v4.y = -o[r][1]; v4.z = -o[r][2]; v4.w = -o[r][3];
        *(float4*)&Ms[(size_t)(I * 64 + 4 * ty + r) * D + J * 64 + 4 * tx] = v4;
    }
}

// ---------------- Kernel 6: fused GEMM + mahalanobis v2 -------------------------
// As stored [il][kk] stride 36: float4 staging (conflict-free), scalar broadcast
// reads in compute. Race between zero-fill and diag-block overwrite removed.
__global__ __launch_bounds__(256) void gemm_maha(const float* __restrict__ M,
                                                 const float* __restrict__ invDT,
                                                 const float* __restrict__ xT,
                                                 const float* __restrict__ mu,
                                                 const float* __restrict__ logdet,
                                                 float* __restrict__ out) {
    const int s = blockIdx.y;
    const int n0 = blockIdx.x * 64;
    const int tid = threadIdx.x, tx = tid & 15, ty = tid >> 4;
    const float* __restrict__ Ms = M + (size_t)s * D * D;
    const float* __restrict__ mus = mu + s * D;
    __shared__ __align__(16) float As[128 * 36];
    __shared__ __align__(16) float Bs[32 * 68];
    __shared__ float red[16 * 68];
    float cs[4] = {0.f, 0.f, 0.f, 0.f};

    for (int ci = 0; ci < 4; ci++) {
        const int i0 = ci * 128;
        float acc[8][4];
#pragma unroll
        for (int r = 0; r < 8; r++)
#pragma unroll
            for (int q = 0; q < 4; q++) acc[r][q] = 0.f;
        const int nkc = (ci + 1) * 4;
        for (int kc = 0; kc < nkc; kc++) {
            const int k0 = kc * 32, kb = k0 >> 6;
            __syncthreads();
            // A-tile: float4 staging from strictly-lower MT; skip diag rows here
            {
                const int g = tid & 7, il0 = tid >> 3;
#pragma unroll
                for (int p = 0; p < 4; p++) {
                    const int il = il0 + 32 * p;
                    const int ib = (i0 + il) >> 6;
                    if (ib != kb) {
                        float4 v = {0.f, 0.f, 0.f, 0.f};
                        if (kb < ib) v = *(const float4*)&Ms[(size_t)(i0 + il) * D + k0 + 4 * g];
                        *(float4*)&As[il * 36 + 4 * g] = v;
                    }
                }
            }
            if (kb >= 2 * ci) {  // diagonal 64-block slice from invDT
                const float* __restrict__ dB = invDT + ((size_t)s * 8 + kb) * 4096
                                             + (size_t)(k0 & 63) * 64;
                const int ilb = (kb - 2 * ci) * 64;
                for (int e = tid; e < 2048; e += 256) {
                    const int ii = e & 63, kk = e >> 6;
                    As[(ilb + ii) * 36 + kk] = dB[kk * 64 + ii];
                }
            }
            for (int e = tid; e < 2048; e += 256) {
                const int nn = e & 63, kk = e >> 6;
                Bs[kk * 68 + nn] = xT[(size_t)(k0 + kk) * 2048 + n0 + nn] - mus[k0 + kk];
            }
            __syncthreads();
#pragma unroll 4
            for (int kk = 0; kk < 32; kk++) {
                const float4 b = *(const float4*)&Bs[kk * 68 + 4 * tx];
                const float bv[4] = {b.x, b.y, b.z, b.w};
                float av[8];
#pragma unroll
                for (int r = 0; r < 8; r++) av[r] = As[(8 * ty + r) * 36 + kk];
#pragma unroll
                for (int r = 0; r < 8; r++)
#pragma unroll
                    for (int q = 0; q < 4; q++) acc[r][q] += av[r] * bv[q];
            }
        }
#pragma unroll
        for (int r = 0; r < 8; r++)
#pragma unroll
            for (int q = 0; q < 4; q++) cs[q] += acc[r][q] * acc[r][q];
    }
    __syncthreads();
#pragma unroll
    for (int q = 0; q < 4; q++) red[ty * 68 + 4 * tx + q] = cs[q];
    __syncthreads();
    if (tid < 64) {
        float mah = 0.f;
#pragma unroll
        for (int t = 0; t < 16; t++) mah += red[t * 68 + tid];
        out[(size_t)(n0 + tid) * 64 + s] = -0.5f * (mah + logdet[s] + 940.993058f);
    }
}

extern "C" void kernel_launch(void* const* d_in, const int* in_sizes, int n_in,
                              void* d_out, int out_size, void* d_ws, size_t ws_size,
                              hipStream_t stream) {
    const float* x  = (const float*)d_in[0];   // (2048, 512)
    const float* mu = (const float*)d_in[1];   // (64, 1, 512)
    const float* sp = (const float*)d_in[3];   // (64, 1, 512, 512)
    float* out = (float*)d_out;                // (2048, 64) fp32

    float* wsf  = (float*)d_ws;
    float* MT   = wsf;                          // 16,777,216 floats
    float* dvec = wsf + (size_t)16777216;       // 32768
    float* evec = dvec + 32768;
    float* lamv = evec + 32768;
    float* logd = lamv + 32768;                 // 64
    float* Vt   = logd + 64;                    // 1,048,576
    float* Wt   = Vt + (size_t)1048576;         // 1,048,576
    float* xT   = Wt + (size_t)1048576;         // 1,048,576
    float* Lp   = Vt;                           // reuse (chol after tridiag)
    float* invDT = Vt;                          // reuse (after chol)

    // 0) transpose x; 1) m = A^T A
    xpose_kernel<<<dim3(32, 8), dim3(256), 0, stream>>>(x, xT);
    syrk_kernel<<<dim3(64, 64), dim3(256), 0, stream>>>(sp, MT);

    // 2) blocked LATRD tridiagonalization
    const size_t plds = (size_t)35924 * sizeof(float);
    for (int p = 0; p < 16; p++) {
        const int ps = 32 * p;
        const int jmax = (p == 15) ? 30 : 32;
        latrd_panel<<<dim3(64), dim3(1024), plds, stream>>>(MT, Vt, Wt, dvec, evec, ps, jmax);
        if (p < 15) {
            const int r0 = ps + 32;
            const int nt = (D - r0 + 63) / 64;
            latrd_update<<<dim3(nt, nt, 64), dim3(256), 0, stream>>>(MT, Vt, Wt, r0);
        }
    }

    // 3) all eigenvalues via Sturm bisection (rcp-based)
    bisect_kernel<<<dim3(4, 64), dim3(128), 0, stream>>>(dvec, evec, lamv);

    // 4) rebuild m, then blocked Cholesky of sigma (L stored transposed in upper)
    syrk_kernel<<<dim3(64, 64), dim3(256), 0, stream>>>(sp, MT);
    const size_t clds = (size_t)(32 * 520 + 4) * sizeof(float);
    for (int p = 0; p < 16; p++) {
        const int j0 = 32 * p;
        chol_panel<<<dim3(64), dim3(256), clds, stream>>>(MT, lamv, logd, Lp, j0, p == 0 ? 1 : 0);
        if (p < 15) {
            const int r0 = j0 + 32;
            const int nt = (D - r0 + 63) / 64;
            chol_update<<<dim3(nt, nt, 64), dim3(256), 0, stream>>>(MT, Lp, r0);
        }
    }

    // 5) full triangular inverse: diag blocks, then off-diag into MT lower
    invdiag_kernel<<<dim3(512), dim3(64), 0, stream>>>(MT, invDT);
    for (int I = 1; I < 8; I++)
        triinv_step<<<dim3(I, 64), dim3(256), 0, stream>>>(MT, invDT, I);

    // 6) fused GEMM + mahalanobis + epilogue
    gemm_maha<<<dim3(32, 64), dim3(256), 0, stream>>>(MT, invDT, xT, mu, logd, out);
}